// Round 14
// baseline (10602.618 us; speedup 1.0000x reference)
//
#include <hip/hip_runtime.h>
#include <cmath>
#include <cstring>
#include <vector>

// ---------------------------------------------------------------------------
// S2ConvNet forward. Round 14:
//  - k9_mfma: SO3 combine on matrix cores. Complex GEMM -> real GEMM via 2x2
//    expansion (K2=2K, N2=2N); bf16 2-term split (hi+lo, 3 MFMAs) keeps rel
//    error ~1e-5 (threshold allows 2%). v_mfma_f32_16x16x32_bf16, 4 waves,
//    16 rows x 64 n2-cols per block. f32 vector gemm3 path retired: it was
//    plateaued at 21 TF with MfmaUtil=0 across 5 structural variants.
//  - rest identical to round 9.
// ---------------------------------------------------------------------------

using sv8 = __attribute__((ext_vector_type(8))) short;   // 8 bf16
using fv4 = __attribute__((ext_vector_type(4))) float;   // 4 f32 acc

__device__ __forceinline__ unsigned short bhi(float v) {
  return (unsigned short)(__float_as_uint(v) >> 16);      // truncating bf16
}
__device__ __forceinline__ float bf2f(unsigned short h) {
  return __uint_as_float(((unsigned)h) << 16);
}

// ======================= table-generation kernels ==========================

__global__ void kg_idx(int4* __restrict__ LMN28, int4* __restrict__ LMN14,
                       int* __restrict__ IDX1) {
  int l = blockIdx.x;                 // 0..27
  int L = 2*l + 1, ofs = l*(4*l*l - 1)/3;
  for (int i = threadIdx.x; i < L*L; i += blockDim.x) {
    int a = i / L, c = i - a*L;
    int4 v = make_int4(l, a - l, c - l, 0);
    LMN28[ofs + i] = v;
    if (l < 14) LMN14[ofs + i] = v;
  }
  for (int a = threadIdx.x; a < L; a += blockDim.x)
    IDX1[l*l + a] = (a - l) + 27;
}

__global__ void kg_tw(float2* __restrict__ E224, float2* __restrict__ EF56,
                      float2* __restrict__ EI56, float2* __restrict__ EF28,
                      float2* __restrict__ EI28) {
  int t = blockIdx.x*256 + threadIdx.x;
  const float TP = 6.283185307179586f;
  if (t < 12320) {                      // E224: 55 x 224, fwd
    int mi = t/224, a = t - mi*224;
    int r = ((mi - 27)*a) % 224;
    float ang = -TP*r/224.f;
    E224[t] = make_float2(cosf(ang), sinf(ang)); return;
  }
  t -= 12320;
  if (t < 1512) {                       // EF56: 27 x 56, fwd
    int ki = t/56, g = t - ki*56;
    int r = ((ki - 13)*g) % 56;
    float ang = -TP*r/56.f;
    EF56[t] = make_float2(cosf(ang), sinf(ang)); return;
  }
  t -= 1512;
  if (t < 3080) {                       // EI56: 56 x 55, inv
    int a = t/55, mi = t - a*55;
    int r = ((mi - 27)*a) % 56;
    float ang = TP*r/56.f;
    EI56[t] = make_float2(cosf(ang), sinf(ang)); return;
  }
  t -= 3080;
  if (t < 756) {                        // EF28: 27 x 28, fwd
    int ki = t/28, g = t - ki*28;
    int r = ((ki - 13)*g) % 28;
    float ang = -TP*r/28.f;
    EF28[t] = make_float2(cosf(ang), sinf(ang)); return;
  }
  t -= 756;
  if (t < 756) {                        // EI28: 28 x 27, inv
    int a = t/27, mi = t - a*27;
    int r = ((mi - 13)*a) % 28;
    float ang = TP*r/28.f;
    EI28[t] = make_float2(cosf(ang), sinf(ang));
  }
}

// Wigner-d tables from eigen-seed
__global__ void kg_wig(const float* __restrict__ VT, const float* __restrict__ LAM,
                       const float* __restrict__ QW, const int4* __restrict__ LMN,
                       float* __restrict__ OUT, int NB, int mode) {
  int spec = blockIdx.x;
  int l, a, c;
  if (mode == 0) {
    l = 0; while ((l+1)*(l+1) <= spec) ++l;
    a = spec - l*l; c = l;
  } else {
    int4 t4 = LMN[spec];
    l = t4.x; a = t4.y + l; c = t4.z + l;
  }
  int n = 2*l + 1;
  const float* V = VT + (size_t)l*(4*l*l - 1)/3;
  const float* lam = LAM + l*l;
  int j = threadIdx.x;
  if (j >= NB) return;
  float be = (j + 0.5f)*(float)M_PI/NB;
  float sc = 0.f, ss = 0.f;
  for (int k = 0; k < n; ++k) {
    float vv = V[a*n + k]*V[c*n + k];
    float x = be*lam[k];
    sc += vv*cosf(x); ss += vv*sinf(x);
  }
  int p = (a - c) & 3;
  float dv = (p==0) ? sc : (p==1) ? -ss : (p==2) ? -sc : ss;
  float w = (mode == 1) ? (float)n : QW[j];
  OUT[(size_t)spec*NB + j] = w*dv;
}

// ============================ pipeline kernels =============================

// ---- Stage 1a: DFT over alpha (224 -> 55 freqs), real input --------------
__global__ void k1_dft_alpha(const float* __restrict__ x,
                             const float2* __restrict__ E,
                             float2* __restrict__ XF) {
  int row = blockIdx.x;                       // z*224 + beta
  __shared__ float r[224];
  for (int i = threadIdx.x; i < 224; i += 64) r[i] = x[(size_t)row*224 + i];
  __syncthreads();
  int mi = threadIdx.x;
  if (mi < 55) {
    float2 acc = make_float2(0.f, 0.f);
    for (int a = 0; a < 224; ++a) {
      float v = r[a];
      float2 e = E[mi*224 + a];
      acc.x += v*e.x; acc.y += v*e.y;
    }
    XF[(size_t)row*55 + mi] = acc;
  }
}

// ---- Stage 1b: S2 Wigner contraction over beta ---------------------------
__global__ void k2_s2wig(const float2* __restrict__ XF,
                         const float* __restrict__ W,
                         const int* __restrict__ IDX,
                         float2* __restrict__ XS) {
  int lm = blockIdx.x;
  int z = threadIdx.x;
  if (z >= 12) return;
  int mi = IDX[lm];
  float2 acc = make_float2(0.f, 0.f);
  for (int b = 0; b < 224; ++b) {
    float w = W[(size_t)lm*224 + b];
    float2 v = XF[((size_t)z*224 + b)*55 + mi];
    acc.x += w*v.x; acc.y += w*v.y;
  }
  XS[lm*12 + z] = acc;
}

// ---- Layer-1 combine ------------------------------------------------------
__global__ void k3_combine1(const float2* __restrict__ XS,
                            const float2* __restrict__ W1,
                            const int4* __restrict__ LMN,
                            float2* __restrict__ ZS) {
  int r = blockIdx.x;
  int4 t = LMN[r];
  int l = t.x, m = t.y, n = t.z;
  int sm = l*l + l + m, sn = l*l + l + n;
  int zb = threadIdx.x >> 5, o = threadIdx.x & 31;
  float2 acc = make_float2(0.f, 0.f);
  #pragma unroll
  for (int i = 0; i < 3; ++i) {
    float2 xv = XS[sm*12 + zb*3 + i];
    float2 wv = W1[(sn*3 + i)*32 + o];
    acc.x += xv.x*wv.x + xv.y*wv.y;   // xv * conj(wv)
    acc.y += xv.y*wv.x - xv.x*wv.y;
  }
  ZS[(size_t)r*128 + threadIdx.x] = acc;
}

// ---- Inverse Wigner: Gp[(mi,ni)][b*ZC+zl] ---------------------------------
template<int NB, int NL>
__global__ void k4_wiginv(const float2* __restrict__ ZS,
                          const float* __restrict__ WT,
                          float2* __restrict__ Gp,
                          int Ztot, int z0, int ZC) {
  constexpr int NF = 2*NL - 1;
  constexpr int NJ = (NB + 7)/8;
  int bx = blockIdx.x;
  int mi = bx / NF, ni = bx % NF;
  int m = mi - (NL-1), n = ni - (NL-1);
  int zl = blockIdx.y*32 + (threadIdx.x & 31);
  int g  = threadIdx.x >> 5;     // 0..7
  float2 acc[NJ];
  #pragma unroll
  for (int j = 0; j < NJ; ++j) acc[j] = make_float2(0.f, 0.f);
  int am = m < 0 ? -m : m, an = n < 0 ? -n : n;
  int lmin = am > an ? am : an;
  for (int l = lmin; l < NL; ++l) {
    int L = 2*l + 1;
    int spec = l*(4*l*l - 1)/3 + (m + l)*L + (n + l);
    float2 zv = ZS[(size_t)spec*Ztot + z0 + zl];
    #pragma unroll
    for (int j = 0; j < NJ; ++j) {
      int b = g + j*8;
      if (b < NB) {
        float w = WT[(size_t)spec*NB + b];
        acc[j].x += w*zv.x; acc[j].y += w*zv.y;
      }
    }
  }
  size_t base = (size_t)bx * ((size_t)ZC*NB) + zl;
  #pragma unroll
  for (int j = 0; j < NJ; ++j) {
    int b = g + j*8;
    if (b < NB) Gp[base + (size_t)b*ZC] = acc[j];
  }
}

// ---- idft stage A ----------------------------------------------------------
template<int NF, int NA>
__global__ __launch_bounds__(256)
void k5a_idft(const float2* __restrict__ G, const float2* __restrict__ EI,
              float2* __restrict__ T2, int rowsC) {
  int ni = blockIdx.x;
  int at = blockIdx.y;
  int row = blockIdx.z*256 + threadIdx.x;
  if (row >= rowsC) return;
  float2 acc[8];
  #pragma unroll
  for (int u = 0; u < 8; ++u) acc[u] = make_float2(0.f, 0.f);
  const float2* gp = G + (size_t)ni*rowsC + row;
  for (int mi = 0; mi < NF; ++mi) {
    float2 gv = gp[(size_t)mi*NF*rowsC];
    #pragma unroll
    for (int u = 0; u < 8; ++u) {
      int a = at*8 + u; if (a >= NA) a = NA-1;       // clamp (result discarded)
      float2 e = EI[a*NF + mi];                      // block-uniform -> s_load
      acc[u].x += e.x*gv.x - e.y*gv.y;
      acc[u].y += e.x*gv.y + e.y*gv.x;
    }
  }
  #pragma unroll
  for (int u = 0; u < 8; ++u) {
    int a = at*8 + u;
    if (a < NA) T2[((size_t)a*NF + ni)*rowsC + row] = acc[u];
  }
}

// ---- idft stage B: contract ni, Re + bias + relu, write Ht[(a,g)][b*Zt+z] --
template<int NF, int NA>
__global__ __launch_bounds__(256)
void k5b_idft(const float2* __restrict__ T2, const float2* __restrict__ EI,
              const float* __restrict__ bias, float* __restrict__ Ht,
              int ZC, int z0, int Zt, int NB, int Cout, int rowsC) {
  constexpr int NAIT = NA/4;
  __shared__ float2 EIs[NA*NF];
  __shared__ float2 Ts[NF][64];
  int a = blockIdx.x;
  int row0 = blockIdx.y*64;
  int t = threadIdx.x;
  for (int i = t; i < NA*NF; i += 256) EIs[i] = EI[i];
  for (int i = t; i < NF*64; i += 256) {
    int ni = i >> 6, rr = i & 63;
    int row = row0 + rr;
    Ts[ni][rr] = (row < rowsC) ? T2[((size_t)a*NF + ni)*rowsC + row]
                               : make_float2(0.f, 0.f);
  }
  __syncthreads();
  int r = t & 63, gq = t >> 6;
  int row = row0 + r;
  if (row >= rowsC) return;
  int b = row / ZC, zl = row - b*ZC;
  int z = z0 + zl;
  float bv = bias[z % Cout];
  float facc[NAIT];
  #pragma unroll
  for (int it = 0; it < NAIT; ++it) facc[it] = 0.f;
  for (int ni = 0; ni < NF; ++ni) {
    float2 tv = Ts[ni][r];
    #pragma unroll
    for (int it = 0; it < NAIT; ++it) {
      float2 e = EIs[(gq + 4*it)*NF + ni];     // wave-uniform -> broadcast
      facc[it] += e.x*tv.x - e.y*tv.y;
    }
  }
  size_t hb = (size_t)(a*NA)*(size_t)(NB*Zt) + (size_t)b*Zt + z;
  #pragma unroll
  for (int it = 0; it < NAIT; ++it) {
    int g = gq + 4*it;
    Ht[hb + (size_t)g*(NB*Zt)] = fmaxf(facc[it] + bv, 0.f);
  }
}

// ---- fwd DFT stage 1 --------------------------------------------------------
template<int NA, int NF>
__global__ __launch_bounds__(256)
void kf1_dftg(const float* __restrict__ Ht, const float2* __restrict__ EF,
              float2* __restrict__ XA, int NB, int Zt, int z0, int ZC, int rowsC) {
  int a = blockIdx.x;
  int kt = blockIdx.y;                 // 0..1 (14 freqs each)
  int row = blockIdx.z*256 + threadIdx.x;
  if (row >= rowsC) return;
  int b = row / ZC, zl = row - b*ZC;
  size_t hbase = (size_t)(a*NA)*(size_t)(NB*Zt) + (size_t)b*Zt + z0 + zl;
  float2 acc[14];
  #pragma unroll
  for (int u = 0; u < 14; ++u) acc[u] = make_float2(0.f, 0.f);
  for (int g = 0; g < NA; ++g) {
    float hv = Ht[hbase + (size_t)g*(NB*Zt)];
    #pragma unroll
    for (int u = 0; u < 14; ++u) {
      int ki = kt*14 + u; if (ki >= NF) ki = NF-1;
      float2 e = EF[ki*NA + g];               // block-uniform -> s_load
      acc[u].x += hv*e.x; acc[u].y += hv*e.y;
    }
  }
  #pragma unroll
  for (int u = 0; u < 14; ++u) {
    int ki = kt*14 + u;
    if (ki < NF) XA[((size_t)a*NF + ki)*rowsC + row] = acc[u];
  }
}

// ---- fwd DFT stage 2 --------------------------------------------------------
template<int NA, int NF>
__global__ __launch_bounds__(256)
void kf2_dfta(const float2* __restrict__ XA, const float2* __restrict__ EF,
              float2* __restrict__ Xf, int rowsC) {
  int ki = blockIdx.x;                 // 0..NF-1
  int mt = blockIdx.y;                 // 0..1
  int row = blockIdx.z*256 + threadIdx.x;
  if (row >= rowsC) return;
  float2 acc[14];
  #pragma unroll
  for (int u = 0; u < 14; ++u) acc[u] = make_float2(0.f, 0.f);
  const float2* xp = XA + (size_t)ki*rowsC + row;
  for (int a = 0; a < NA; ++a) {
    float2 v = xp[(size_t)a*NF*rowsC];
    #pragma unroll
    for (int u = 0; u < 14; ++u) {
      int mi = mt*14 + u; if (mi >= NF) mi = NF-1;
      float2 e = EF[mi*NA + a];
      acc[u].x += v.x*e.x - v.y*e.y;
      acc[u].y += v.x*e.y + v.y*e.x;
    }
  }
  #pragma unroll
  for (int u = 0; u < 14; ++u) {
    int mi = mt*14 + u;
    if (mi < NF) Xf[((size_t)mi*NF + ki)*rowsC + row] = acc[u];
  }
}

// ---- forward Wigner --------------------------------------------------------
__global__ void k8_wigfwd(const float2* __restrict__ XfT,
                          const float* __restrict__ WT,
                          const int4* __restrict__ LMN,
                          float2* __restrict__ XS,
                          int NB, int ZC, int z0, int Ztot) {
  int spec = blockIdx.x;
  int zl = threadIdx.x;
  int4 t = LMN[spec];
  int mi = t.y + 13, ni = t.z + 13;
  float2 acc = make_float2(0.f, 0.f);
  size_t base = (size_t)(mi*27 + ni) * ((size_t)NB*ZC);
  for (int b = 0; b < NB; ++b) {
    float w = WT[(size_t)spec*NB + b];
    float2 v = XfT[base + (size_t)b*ZC + zl];
    acc.x += w*v.x; acc.y += w*v.y;
  }
  XS[(size_t)spec*Ztot + z0 + zl] = acc;
}

// ---- SO3 combine on MFMA (bf16 split, complex->real 2x2 expansion) --------
// C = conj(X)[M x K] * W[K x N] complex. Real form: A2[M][2K], B2[2K][2N]:
//   A2[r][2k]=Xr, A2[r][2k+1]=-Xi  (conj)
//   B2[2k][2n]=Wr, B2[2k+1][2n]=-Wi, B2[2k][2n+1]=Wi, B2[2k+1][2n+1]=Wr
// -> C2[r][2n]=Re, C2[r][2n+1]=Im.  bf16 2-term split: 3 MFMAs/tile.
// Block: 16 rows x 64 n2-cols; 4 waves, wave w owns cols w*16..+16; K2 step 32.
// packed task: l | (m0/16)<<4 | (c0/64)<<8
template<int CI, int CO>
__global__ __launch_bounds__(256)
void k9_mfma(const float2* __restrict__ XS, const float2* __restrict__ W,
             const int* __restrict__ tasks, float* __restrict__ ZSo) {
  constexpr int Zin = 4*CI, Zout = 4*CO;
  constexpr int LOG2CI = (CI==32) ? 5 : (CI==64) ? 6 : 7;
  int pk = tasks[blockIdx.x];
  int l  = pk & 15;
  int m0 = ((pk >> 4) & 15)*16;
  int c0 = (pk >> 8)*64;
  int L = 2*l + 1;
  int ofs = l*(4*l*l - 1)/3;
  int M = 4*L, K = L*CI, N2 = 2*L*CO;
  __shared__ __align__(16) unsigned short Ah[16][40], Al[16][40];
  __shared__ __align__(16) unsigned short Bh[64][40], Bl[64][40];
  int t = threadIdx.x;
  int wv = t >> 6, ln = t & 63;
  int frow = ln & 15, fkg = ln >> 4;
  fv4 acc = {0.f, 0.f, 0.f, 0.f};

  // A staging coords
  int ar = t >> 4, atc = t & 15;
  int AR = m0 + ar;
  int am = AR >> 2, azb = AR & 3;
  bool aok = AR < M;
  int nc0 = c0 >> 1;

  for (int k20 = 0; k20 < 2*K; k20 += 32) {
    int kc0 = k20 >> 1;
    // ---- stage A tile: 16 rows x 16 complex-k ----
    {
      int kc = kc0 + atc;
      float xr = 0.f, xi = 0.f;
      if (aok) {
        int kq = kc >> LOG2CI, ii = kc & (CI-1);
        float2 xv = XS[((size_t)(ofs + am*L + kq))*Zin + (size_t)azb*CI + ii];
        xr = xv.x; xi = -xv.y;
      }
      unsigned short rh = bhi(xr); unsigned short rl = bhi(xr - bf2f(rh));
      unsigned short ih = bhi(xi); unsigned short il = bhi(xi - bf2f(ih));
      *(unsigned*)&Ah[ar][2*atc] = (unsigned)rh | ((unsigned)ih << 16);
      *(unsigned*)&Al[ar][2*atc] = (unsigned)rl | ((unsigned)il << 16);
    }
    // ---- stage B tile: 16 complex-k x 32 complex-n ----
    #pragma unroll
    for (int h = 0; h < 2; ++h) {
      int idx = t + 256*h;
      int kci = idx >> 5, nci = idx & 31;
      int kc = kc0 + kci;
      int nc = nc0 + nci;
      float wr = 0.f, wi = 0.f;
      if (nc < L*CO) {
        int n = nc / CO, o = nc - n*CO;
        int kq = kc >> LOG2CI, ii = kc & (CI-1);
        float2 wvv = W[((size_t)(ofs + n*L + kq)*CI + ii)*CO + o];
        wr = wvv.x; wi = wvv.y;
      }
      unsigned short rh = bhi(wr); unsigned short rl = bhi(wr - bf2f(rh));
      unsigned short ih = bhi(wi); unsigned short il = bhi(wi - bf2f(ih));
      // row 2nci: (Wr, -Wi) ; row 2nci+1: (Wi, Wr)
      *(unsigned*)&Bh[2*nci][2*kci]     = (unsigned)rh | ((unsigned)(ih ^ 0x8000) << 16);
      *(unsigned*)&Bh[2*nci + 1][2*kci] = (unsigned)ih | ((unsigned)rh << 16);
      *(unsigned*)&Bl[2*nci][2*kci]     = (unsigned)rl | ((unsigned)(il ^ 0x8000) << 16);
      *(unsigned*)&Bl[2*nci + 1][2*kci] = (unsigned)il | ((unsigned)rl << 16);
    }
    __syncthreads();
    sv8 fah = *(const sv8*)&Ah[frow][fkg*8];
    sv8 fal = *(const sv8*)&Al[frow][fkg*8];
    sv8 fbh = *(const sv8*)&Bh[wv*16 + frow][fkg*8];
    sv8 fbl = *(const sv8*)&Bl[wv*16 + frow][fkg*8];
    acc = __builtin_amdgcn_mfma_f32_16x16x32_bf16(fah, fbh, acc, 0, 0, 0);
    acc = __builtin_amdgcn_mfma_f32_16x16x32_bf16(fah, fbl, acc, 0, 0, 0);
    acc = __builtin_amdgcn_mfma_f32_16x16x32_bf16(fal, fbh, acc, 0, 0, 0);
    __syncthreads();
  }
  // epilogue: C/D layout (verified): col = lane&15, row = (lane>>4)*4 + reg
  int col = ln & 15;
  int n2 = c0 + wv*16 + col;
  if (n2 < N2) {
    int nc = n2 >> 1, comp = n2 & 1;
    int n = nc / CO, o = nc - n*CO;
    #pragma unroll
    for (int g = 0; g < 4; ++g) {
      int R = m0 + (ln >> 4)*4 + g;
      if (R < M) {
        int m = R >> 2, zb = R & 3;
        ZSo[(((size_t)(ofs + m*L + n))*Zout + (size_t)zb*CO + o)*2 + comp] = acc[g];
      }
    }
  }
}

// ---- integrate (Ht layout) + FC -------------------------------------------
__global__ void k10a_colsum(const float* __restrict__ Ht, float* __restrict__ Cp,
                            int rows, int cols, int rowsPer) {
  int col = blockIdx.x*256 + threadIdx.x;
  if (col >= cols) return;
  int r0 = blockIdx.y*rowsPer;
  int r1 = r0 + rowsPer; if (r1 > rows) r1 = rows;
  float acc = 0.f;
  for (int r = r0; r < r1; ++r) acc += Ht[(size_t)r*cols + col];
  Cp[(size_t)blockIdx.y*cols + col] = acc;
}

__global__ void k10a_fin(const float* __restrict__ Cp, const float* __restrict__ QW,
                         float* __restrict__ S, int Zt, int NB, int nparts) {
  int z = blockIdx.x*64 + threadIdx.x;
  if (z >= Zt) return;
  int cols = NB*Zt;
  float acc = 0.f;
  for (int b = 0; b < NB; ++b) {
    float cs = 0.f;
    for (int p = 0; p < nparts; ++p) cs += Cp[(size_t)p*cols + b*Zt + z];
    acc += cs * QW[b];
  }
  S[z] = acc;
}

__global__ void k10b_fc(const float* __restrict__ S,
                        const float* __restrict__ Wout,
                        const float* __restrict__ bout,
                        float* __restrict__ out) {
  int t = threadIdx.x;
  if (t < 40) {
    int zb = t / 10, c = t % 10;
    float acc = bout[c];
    for (int o = 0; o < 40; ++o) acc += S[zb*40 + o] * Wout[c*40 + o];
    out[zb*10 + c] = acc;
  }
}

// ===========================================================================
// Host side
// ===========================================================================

// upload blob offsets (bytes)
static const size_t U_VT    = 0;                     // 29260 f
static const size_t U_LAM   = 117040;                // 784 f
static const size_t U_QW224 = U_LAM + 3136;          // 224 f
static const size_t U_QW56  = U_QW224 + 896;         // 56 f
static const size_t U_QW28  = U_QW56 + 224;          // 28 f
static const size_t U_TK2   = U_QW28 + 112;          // 6144 int each
static const size_t U_TK3   = U_TK2 + 24576;
static const size_t U_TK4   = U_TK3 + 24576;
static const size_t U_TK5   = U_TK4 + 24576;
static const size_t U_BYTES = U_TK5 + 24576;

struct WsOff {
  size_t up, ws2t, wi28t, wf28t, wi14t, wf14t, e224, ef56, ei56, ef28, ei28,
         lmn28, lmn14, idx1, zs1, xsf, zso, HA, HB, S, fixedEnd;
};

static WsOff wsOff() {
  WsOff o; size_t c = 0;
  auto take = [&](size_t bytes) { size_t r = c; c = (c + bytes + 255) & ~(size_t)255; return r; };
  o.up    = take(U_BYTES);
  o.ws2t  = take((size_t)784*224*4);
  o.wi28t = take((size_t)29260*56*4);
  o.wf28t = take((size_t)3654*56*4);
  o.wi14t = take((size_t)3654*28*4);
  o.wf14t = take((size_t)3654*28*4);
  o.e224  = take((size_t)55*224*8);
  o.ef56  = take((size_t)27*56*8);
  o.ei56  = take((size_t)56*55*8);
  o.ef28  = take((size_t)27*28*8);
  o.ei28  = take((size_t)28*27*8);
  o.lmn28 = take((size_t)29260*16);
  o.lmn14 = take((size_t)3654*16);
  o.idx1  = take(784*4);
  o.zs1   = take((size_t)29260*128*8);
  o.xsf   = take((size_t)3654*512*8);
  o.zso   = take((size_t)3654*512*8);
  o.HA    = take((size_t)128*56*56*56*4);
  o.HB    = take((size_t)512*28*28*28*4);
  o.S     = take(16*4480*4 + 1024);
  o.fixedEnd = c;
  return o;
}

// Jacobi eigensolver for symmetric n x n (n <= 55), A destroyed.
static void jacobi_sym(int n, double* A, double* V, double* lam) {
  for (int i = 0; i < n*n; ++i) V[i] = 0.0;
  for (int i = 0; i < n; ++i) V[i*n + i] = 1.0;
  for (int sweep = 0; sweep < 100; ++sweep) {
    double off = 0.0;
    for (int p = 0; p < n; ++p)
      for (int q = p+1; q < n; ++q) off += A[p*n+q]*A[p*n+q];
    if (off < 1e-22) break;
    for (int p = 0; p < n-1; ++p) {
      for (int q = p+1; q < n; ++q) {
        double apq = A[p*n+q];
        if (fabs(apq) < 1e-300) continue;
        double theta = (A[q*n+q] - A[p*n+p]) / (2.0*apq);
        double tt = (theta >= 0 ? 1.0 : -1.0) / (fabs(theta) + sqrt(theta*theta + 1.0));
        double cc = 1.0/sqrt(tt*tt + 1.0), ss = tt*cc;
        for (int i = 0; i < n; ++i) {
          double aip = A[i*n+p], aiq = A[i*n+q];
          A[i*n+p] = cc*aip - ss*aiq;
          A[i*n+q] = ss*aip + cc*aiq;
        }
        for (int i = 0; i < n; ++i) {
          double api = A[p*n+i], aqi = A[q*n+i];
          A[p*n+i] = cc*api - ss*aqi;
          A[q*n+i] = ss*api + cc*aqi;
        }
        for (int i = 0; i < n; ++i) {
          double vip = V[i*n+p], viq = V[i*n+q];
          V[i*n+p] = cc*vip - ss*viq;
          V[i*n+q] = ss*vip + cc*viq;
        }
      }
    }
  }
  for (int i = 0; i < n; ++i) lam[i] = A[i*n+i];
}

extern "C" void kernel_launch(void* const* d_in, const int* in_sizes, int n_in,
                              void* d_out, int out_size, void* d_ws, size_t ws_size,
                              hipStream_t stream) {
  (void)in_sizes; (void)n_in; (void)out_size;
  const WsOff off = wsOff();
  const size_t MINAB = (size_t)3080*32*56*8;      // 44.2 MB: layer-1 T2 chunk
  if (ws_size < off.fixedEnd + 2*MINAB) return;

  const float*  x    = (const float*)d_in[0];
  const float2* w1   = (const float2*)d_in[1];
  const float*  b1   = (const float*)d_in[2];
  const float2* w2   = (const float2*)d_in[3];
  const float*  b2   = (const float*)d_in[4];
  const float2* w3   = (const float2*)d_in[5];
  const float*  b3   = (const float*)d_in[6];
  const float2* w4   = (const float2*)d_in[7];
  const float*  b4   = (const float*)d_in[8];
  const float2* w5   = (const float2*)d_in[9];
  const float*  b5   = (const float*)d_in[10];
  const float*  wout = (const float*)d_in[11];
  const float*  bout = (const float*)d_in[12];
  float* outp = (float*)d_out;
  char* ws = (char*)d_ws;

  // ------------- host: eigen-seeds + quad weights + task tables -----------
  char* hb = new char[U_BYTES];                 // leaked; graph keeps the ptr
  memset(hb, 0, U_BYTES);
  float* hVT  = (float*)(hb + U_VT);
  float* hLAM = (float*)(hb + U_LAM);
  float* hQW224 = (float*)(hb + U_QW224);
  float* hQW56  = (float*)(hb + U_QW56);
  float* hQW28  = (float*)(hb + U_QW28);
  int*   hTK[4] = {(int*)(hb + U_TK2), (int*)(hb + U_TK3),
                   (int*)(hb + U_TK4), (int*)(hb + U_TK5)};

  auto quadw = [](int b, double* w) {
    for (int j = 0; j < 2*b; ++j) {
      double s = 0.0;
      for (int k = 0; k < b; ++k)
        s += sin(M_PI*(2*j+1)*(2*k+1)/(4.0*b)) / (double)(2*k+1);
      w[j] = 2.0/b * sin(M_PI*(2*j+1)/(4.0*b)) * s * 2.0*M_PI/((2.0*b)*(2.0*b));
    }
  };
  std::vector<double> qw224(224), qw56(56), qw28v(28);
  quadw(112, qw224.data()); quadw(28, qw56.data()); quadw(14, qw28v.data());
  for (int j = 0; j < 224; ++j) hQW224[j] = (float)qw224[j];
  for (int j = 0; j < 56;  ++j) hQW56[j]  = (float)qw56[j];
  for (int j = 0; j < 28;  ++j) hQW28[j]  = (float)qw28v[j];

  const int NMAX = 55;
  std::vector<double> T(NMAX*NMAX), V(NMAX*NMAX), lam(NMAX);
  for (int l = 0; l < 28; ++l) {
    int n = 2*l + 1;
    std::fill(T.begin(), T.begin() + n*n, 0.0);
    for (int i = 0; i < n-1; ++i) {
      int m = i - l;
      double c = sqrt((double)(l*(l+1)) - (double)(m*(m+1)));
      T[i*n + i + 1] = 0.5*c;
      T[(i+1)*n + i] = 0.5*c;
    }
    jacobi_sym(n, T.data(), V.data(), lam.data());
    size_t vofs = (size_t)l*(4*l*l - 1)/3;
    for (int i = 0; i < n*n; ++i) hVT[vofs + i] = (float)V[i];
    for (int k = 0; k < n; ++k)  hLAM[l*l + k] = (float)lam[k];
  }

  // MFMA task tables: packed l | (m0/16)<<4 | (c0/64)<<8 ; l descending,
  // m0 inner (same-c0 siblings adjacent -> B-tile L2 reuse)
  const int COv[4] = {64, 128, 64, 40};
  int tcnt[4];
  for (int li = 0; li < 4; ++li) {
    int cnt = 0;
    for (int l = 13; l >= 0; --l) {
      int L = 2*l + 1, M = 4*L, N2 = 2*L*COv[li];
      for (int c0 = 0; c0 < N2; c0 += 64)
        for (int m0 = 0; m0 < M; m0 += 16)
          hTK[li][cnt++] = l | ((m0/16) << 4) | ((c0/64) << 8);
    }
    tcnt[li] = cnt;   // ~2016, ~4032, ~2016, ~1282 (<= 6144)
  }

  // ------------------- device pointers -------------------
  const float*  dWS2T  = (const float*)(ws + off.ws2t);
  const float*  dWI28T = (const float*)(ws + off.wi28t);
  const float*  dWF28T = (const float*)(ws + off.wf28t);
  const float*  dWI14T = (const float*)(ws + off.wi14t);
  const float*  dWF14T = (const float*)(ws + off.wf14t);
  const float2* dE224  = (const float2*)(ws + off.e224);
  const float2* dEF56  = (const float2*)(ws + off.ef56);
  const float2* dEI56  = (const float2*)(ws + off.ei56);
  const float2* dEF28  = (const float2*)(ws + off.ef28);
  const float2* dEI28  = (const float2*)(ws + off.ei28);
  const int4*   dLMN28 = (const int4*)(ws + off.lmn28);
  const int4*   dLMN14 = (const int4*)(ws + off.lmn14);
  const int*    dIDX1  = (const int*)(ws + off.idx1);
  const float*  dUVT   = (const float*)(ws + off.up + U_VT);
  const float*  dULAM  = (const float*)(ws + off.up + U_LAM);
  const float*  dUQW224= (const float*)(ws + off.up + U_QW224);
  const float*  dUQW56 = (const float*)(ws + off.up + U_QW56);
  const float*  dUQW28 = (const float*)(ws + off.up + U_QW28);
  const int*    dTK2   = (const int*)(ws + off.up + U_TK2);
  const int*    dTK3   = (const int*)(ws + off.up + U_TK3);
  const int*    dTK4   = (const int*)(ws + off.up + U_TK4);
  const int*    dTK5   = (const int*)(ws + off.up + U_TK5);
  float2* dZS1 = (float2*)(ws + off.zs1);
  float2* dXSF = (float2*)(ws + off.xsf);
  float2* dZSO = (float2*)(ws + off.zso);
  float*  dHA  = (float*)(ws + off.HA);
  float*  dHB  = (float*)(ws + off.HB);
  float*  dCp  = (float*)(ws + off.S);                  // 16 x 4480 partials
  float*  dS   = (float*)(ws + off.S + 16*4480*4);      // 160 sums

  size_t ab = ((ws_size - off.fixedEnd)/2) & ~(size_t)255;
  char* Abuf = ws + off.fixedEnd;
  char* Bbuf = Abuf + ab;
  float2* dA = (float2*)Abuf;
  float2* dB = (float2*)Bbuf;
  // xf1/xs1 alias the A buffer (dead before first k4 use of A)
  float2* dXF1 = (float2*)Abuf;                          // 12*224*55 f2
  float2* dXS1 = (float2*)(Abuf + 1182720);              // 784*12 f2

  // ------------------- upload seeds + generate tables -------------------
  hipMemcpyAsync(ws + off.up, hb, U_BYTES, hipMemcpyHostToDevice, stream);
  kg_idx<<<28, 256, 0, stream>>>((int4*)(ws + off.lmn28), (int4*)(ws + off.lmn14),
                                 (int*)(ws + off.idx1));
  kg_tw<<<72, 256, 0, stream>>>((float2*)(ws + off.e224), (float2*)(ws + off.ef56),
                                (float2*)(ws + off.ei56), (float2*)(ws + off.ef28),
                                (float2*)(ws + off.ei28));
  kg_wig<<<784, 224, 0, stream>>>(dUVT, dULAM, dUQW224, nullptr,
                                  (float*)(ws + off.ws2t), 224, 0);
  kg_wig<<<29260, 64, 0, stream>>>(dUVT, dULAM, nullptr, dLMN28,
                                   (float*)(ws + off.wi28t), 56, 1);
  kg_wig<<<3654, 64, 0, stream>>>(dUVT, dULAM, dUQW56, dLMN14,
                                  (float*)(ws + off.wf28t), 56, 2);
  kg_wig<<<3654, 64, 0, stream>>>(dUVT, dULAM, nullptr, dLMN14,
                                  (float*)(ws + off.wi14t), 28, 1);
  kg_wig<<<3654, 64, 0, stream>>>(dUVT, dULAM, dUQW28, dLMN14,
                                  (float*)(ws + off.wf14t), 28, 2);

  // chunk pickers (bytes-per-z of the largest chunk buffer)
  auto pickPow2 = [&](int Zt, size_t perz)->int {
    int zc = Zt;
    while (zc > 32 && perz*(size_t)zc > ab) zc >>= 1;
    return zc;
  };
  int zc1  = pickPow2(128, (size_t)3080*56*8);   // layer-1 inverse (T2 biggest)
  int zcF2 = pickPow2(128, (size_t)56*27*56*8);  // layer-2 fwd (XA biggest)
  int zcI  = pickPow2(256, (size_t)756*28*8);    // b=14 inverse
  int zcF  = pickPow2(256, (size_t)28*27*28*8);  // b=14 fwd (Zt<=512 chunks)

  // ------------------- layer 1: s2_conv(112 -> 28) -------------------
  k1_dft_alpha<<<12*224, 64, 0, stream>>>(x, dE224, dXF1);
  k2_s2wig<<<784, 64, 0, stream>>>(dXF1, dWS2T, dIDX1, dXS1);
  k3_combine1<<<29260, 128, 0, stream>>>(dXS1, w1, dLMN28, dZS1);
  for (int z0 = 0; z0 < 128; z0 += zc1) {
    int rowsC = zc1*56;
    k4_wiginv<56,28><<<dim3(3025, zc1/32), 256, 0, stream>>>(dZS1, dWI28T, dA, 128, z0, zc1);
    k5a_idft<55,56><<<dim3(55, 7, (rowsC+255)/256), 256, 0, stream>>>(dA, dEI56, dB, rowsC);
    k5b_idft<55,56><<<dim3(56, (rowsC+63)/64), 256, 0, stream>>>(dB, dEI56, b1, dHA,
                                                                 zc1, z0, 128, 56, 32, rowsC);
  }

  // ------------------- layer 2: so3_conv(28 -> 14), 32->64 -----------
  for (int z0 = 0; z0 < 128; z0 += zcF2) {
    int rowsC = zcF2*56;
    kf1_dftg<56,27><<<dim3(56, 2, (rowsC+255)/256), 256, 0, stream>>>(dHA, dEF56, dA,
                                                                      56, 128, z0, zcF2, rowsC);
    kf2_dfta<56,27><<<dim3(27, 2, (rowsC+255)/256), 256, 0, stream>>>(dA, dEF56, dB, rowsC);
    k8_wigfwd<<<3654, zcF2, 0, stream>>>(dB, dWF28T, dLMN14, dXSF, 56, zcF2, z0, 128);
  }
  k9_mfma<32,64><<<tcnt[0], 256, 0, stream>>>(dXSF, w2, dTK2, (float*)dZSO);
  for (int z0 = 0; z0 < 256; z0 += zcI) {
    int rowsC = zcI*28;
    k4_wiginv<28,14><<<dim3(729, zcI/32), 256, 0, stream>>>(dZSO, dWI14T, dA, 256, z0, zcI);
    k5a_idft<27,28><<<dim3(27, 4, (rowsC+255)/256), 256, 0, stream>>>(dA, dEI28, dB, rowsC);
    k5b_idft<27,28><<<dim3(28, (rowsC+63)/64), 256, 0, stream>>>(dB, dEI28, b2, dHB,
                                                                 zcI, z0, 256, 28, 64, rowsC);
  }

  // ------------------- layer 3: so3_conv(14), 64->128 ----------------
  for (int z0 = 0; z0 < 256; z0 += zcF) {
    int rowsC = zcF*28;
    kf1_dftg<28,27><<<dim3(28, 2, (rowsC+255)/256), 256, 0, stream>>>(dHB, dEF28, dA,
                                                                      28, 256, z0, zcF, rowsC);
    kf2_dfta<28,27><<<dim3(27, 2, (rowsC+255)/256), 256, 0, stream>>>(dA, dEF28, dB, rowsC);
    k8_wigfwd<<<3654, zcF, 0, stream>>>(dB, dWF14T, dLMN14, dXSF, 28, zcF, z0, 256);
  }
  k9_mfma<64,128><<<tcnt[1], 256, 0, stream>>>(dXSF, w3, dTK3, (float*)dZSO);
  for (int z0 = 0; z0 < 512; z0 += zcI) {
    int rowsC = zcI*28;
    k4_wiginv<28,14><<<dim3(729, zcI/32), 256, 0, stream>>>(dZSO, dWI14T, dA, 512, z0, zcI);
    k5a_idft<27,28><<<dim3(27, 4, (rowsC+255)/256), 256, 0, stream>>>(dA, dEI28, dB, rowsC);
    k5b_idft<27,28><<<dim3(28, (rowsC+63)/64), 256, 0, stream>>>(dB, dEI28, b3, dHA,
                                                                 zcI, z0, 512, 28, 128, rowsC);
  }

  // ------------------- layer 4: so3_conv(14), 128->64 ----------------
  for (int z0 = 0; z0 < 512; z0 += zcF) {
    int rowsC = zcF*28;
    kf1_dftg<28,27><<<dim3(28, 2, (rowsC+255)/256), 256, 0, stream>>>(dHA, dEF28, dA,
                                                                      28, 512, z0, zcF, rowsC);
    kf2_dfta<28,27><<<dim3(27, 2, (rowsC+255)/256), 256, 0, stream>>>(dA, dEF28, dB, rowsC);
    k8_wigfwd<<<3654, zcF, 0, stream>>>(dB, dWF14T, dLMN14, dXSF, 28, zcF, z0, 512);
  }
  k9_mfma<128,64><<<tcnt[2], 256, 0, stream>>>(dXSF, w4, dTK4, (float*)dZSO);
  for (int z0 = 0; z0 < 256; z0 += zcI) {
    int rowsC = zcI*28;
    k4_wiginv<28,14><<<dim3(729, zcI/32), 256, 0, stream>>>(dZSO, dWI14T, dA, 256, z0, zcI);
    k5a_idft<27,28><<<dim3(27, 4, (rowsC+255)/256), 256, 0, stream>>>(dA, dEI28, dB, rowsC);
    k5b_idft<27,28><<<dim3(28, (rowsC+63)/64), 256, 0, stream>>>(dB, dEI28, b4, dHB,
                                                                 zcI, z0, 256, 28, 64, rowsC);
  }

  // ------------------- layer 5: so3_conv(14), 64->40 -----------------
  for (int z0 = 0; z0 < 256; z0 += zcF) {
    int rowsC = zcF*28;
    kf1_dftg<28,27><<<dim3(28, 2, (rowsC+255)/256), 256, 0, stream>>>(dHB, dEF28, dA,
                                                                      28, 256, z0, zcF, rowsC);
    kf2_dfta<28,27><<<dim3(27, 2, (rowsC+255)/256), 256, 0, stream>>>(dA, dEF28, dB, rowsC);
    k8_wigfwd<<<3654, zcF, 0, stream>>>(dB, dWF14T, dLMN14, dXSF, 28, zcF, z0, 256);
  }
  k9_mfma<64,40><<<tcnt[3], 256, 0, stream>>>(dXSF, w5, dTK5, (float*)dZSO);
  {
    // Z = 160 in one chunk (T2 = 27 MB <= ab)
    int rowsC = 160*28;
    k4_wiginv<28,14><<<dim3(729, 5), 256, 0, stream>>>(dZSO, dWI14T, dA, 160, 0, 160);
    k5a_idft<27,28><<<dim3(27, 4, (rowsC+255)/256), 256, 0, stream>>>(dA, dEI28, dB, rowsC);
    k5b_idft<27,28><<<dim3(28, (rowsC+63)/64), 256, 0, stream>>>(dB, dEI28, b5, dHA,
                                                                 160, 0, 160, 28, 40, rowsC);
  }

  // ------------------- integrate + FC -------------------
  k10a_colsum<<<dim3(18, 16), 256, 0, stream>>>(dHA, dCp, 784, 4480, 49);
  k10a_fin<<<3, 64, 0, stream>>>(dCp, dUQW28, dS, 160, 28, 16);
  k10b_fc<<<1, 64, 0, stream>>>(dS, wout, bout, outp);
}

// Round 15
// 4028.914 us; speedup vs baseline: 2.6316x; 2.6316x over previous
//
#include <hip/hip_runtime.h>
#include <cmath>
#include <cstring>
#include <vector>

// ---------------------------------------------------------------------------
// S2ConvNet forward. Round 15:
//  - k9_mfma2: full-M blocks (W streamed exactly once; task=(l,c0)); swizzled
//    flat LDS (frag slot = mt*64+lane -> conflict-free b128 reads); acc[7]
//    static-unrolled. Round-14 version re-fetched W ~3x (746 MB/dispatch) and
//    had 1.8e8 bank conflicts.
//  - kf1_dftg: 7-wide load batching (was latency-bound: 978us at 4% VALU).
//  - rest identical to round 14.
// ---------------------------------------------------------------------------

using sv8 = __attribute__((ext_vector_type(8))) short;   // 8 bf16
using fv4 = __attribute__((ext_vector_type(4))) float;   // 4 f32 acc

__device__ __forceinline__ unsigned short bhi(float v) {
  return (unsigned short)(__float_as_uint(v) >> 16);      // truncating bf16
}
__device__ __forceinline__ float bf2f(unsigned short h) {
  return __uint_as_float(((unsigned)h) << 16);
}

// ======================= table-generation kernels ==========================

__global__ void kg_idx(int4* __restrict__ LMN28, int4* __restrict__ LMN14,
                       int* __restrict__ IDX1) {
  int l = blockIdx.x;                 // 0..27
  int L = 2*l + 1, ofs = l*(4*l*l - 1)/3;
  for (int i = threadIdx.x; i < L*L; i += blockDim.x) {
    int a = i / L, c = i - a*L;
    int4 v = make_int4(l, a - l, c - l, 0);
    LMN28[ofs + i] = v;
    if (l < 14) LMN14[ofs + i] = v;
  }
  for (int a = threadIdx.x; a < L; a += blockDim.x)
    IDX1[l*l + a] = (a - l) + 27;
}

__global__ void kg_tw(float2* __restrict__ E224, float2* __restrict__ EF56,
                      float2* __restrict__ EI56, float2* __restrict__ EF28,
                      float2* __restrict__ EI28) {
  int t = blockIdx.x*256 + threadIdx.x;
  const float TP = 6.283185307179586f;
  if (t < 12320) {                      // E224: 55 x 224, fwd
    int mi = t/224, a = t - mi*224;
    int r = ((mi - 27)*a) % 224;
    float ang = -TP*r/224.f;
    E224[t] = make_float2(cosf(ang), sinf(ang)); return;
  }
  t -= 12320;
  if (t < 1512) {                       // EF56: 27 x 56, fwd
    int ki = t/56, g = t - ki*56;
    int r = ((ki - 13)*g) % 56;
    float ang = -TP*r/56.f;
    EF56[t] = make_float2(cosf(ang), sinf(ang)); return;
  }
  t -= 1512;
  if (t < 3080) {                       // EI56: 56 x 55, inv
    int a = t/55, mi = t - a*55;
    int r = ((mi - 27)*a) % 56;
    float ang = TP*r/56.f;
    EI56[t] = make_float2(cosf(ang), sinf(ang)); return;
  }
  t -= 3080;
  if (t < 756) {                        // EF28: 27 x 28, fwd
    int ki = t/28, g = t - ki*28;
    int r = ((ki - 13)*g) % 28;
    float ang = -TP*r/28.f;
    EF28[t] = make_float2(cosf(ang), sinf(ang)); return;
  }
  t -= 756;
  if (t < 756) {                        // EI28: 28 x 27, inv
    int a = t/27, mi = t - a*27;
    int r = ((mi - 13)*a) % 28;
    float ang = TP*r/28.f;
    EI28[t] = make_float2(cosf(ang), sinf(ang));
  }
}

// Wigner-d tables from eigen-seed
__global__ void kg_wig(const float* __restrict__ VT, const float* __restrict__ LAM,
                       const float* __restrict__ QW, const int4* __restrict__ LMN,
                       float* __restrict__ OUT, int NB, int mode) {
  int spec = blockIdx.x;
  int l, a, c;
  if (mode == 0) {
    l = 0; while ((l+1)*(l+1) <= spec) ++l;
    a = spec - l*l; c = l;
  } else {
    int4 t4 = LMN[spec];
    l = t4.x; a = t4.y + l; c = t4.z + l;
  }
  int n = 2*l + 1;
  const float* V = VT + (size_t)l*(4*l*l - 1)/3;
  const float* lam = LAM + l*l;
  int j = threadIdx.x;
  if (j >= NB) return;
  float be = (j + 0.5f)*(float)M_PI/NB;
  float sc = 0.f, ss = 0.f;
  for (int k = 0; k < n; ++k) {
    float vv = V[a*n + k]*V[c*n + k];
    float x = be*lam[k];
    sc += vv*cosf(x); ss += vv*sinf(x);
  }
  int p = (a - c) & 3;
  float dv = (p==0) ? sc : (p==1) ? -ss : (p==2) ? -sc : ss;
  float w = (mode == 1) ? (float)n : QW[j];
  OUT[(size_t)spec*NB + j] = w*dv;
}

// ============================ pipeline kernels =============================

// ---- Stage 1a: DFT over alpha (224 -> 55 freqs), real input --------------
__global__ void k1_dft_alpha(const float* __restrict__ x,
                             const float2* __restrict__ E,
                             float2* __restrict__ XF) {
  int row = blockIdx.x;                       // z*224 + beta
  __shared__ float r[224];
  for (int i = threadIdx.x; i < 224; i += 64) r[i] = x[(size_t)row*224 + i];
  __syncthreads();
  int mi = threadIdx.x;
  if (mi < 55) {
    float2 acc = make_float2(0.f, 0.f);
    for (int a = 0; a < 224; ++a) {
      float v = r[a];
      float2 e = E[mi*224 + a];
      acc.x += v*e.x; acc.y += v*e.y;
    }
    XF[(size_t)row*55 + mi] = acc;
  }
}

// ---- Stage 1b: S2 Wigner contraction over beta ---------------------------
__global__ void k2_s2wig(const float2* __restrict__ XF,
                         const float* __restrict__ W,
                         const int* __restrict__ IDX,
                         float2* __restrict__ XS) {
  int lm = blockIdx.x;
  int z = threadIdx.x;
  if (z >= 12) return;
  int mi = IDX[lm];
  float2 acc = make_float2(0.f, 0.f);
  for (int b = 0; b < 224; ++b) {
    float w = W[(size_t)lm*224 + b];
    float2 v = XF[((size_t)z*224 + b)*55 + mi];
    acc.x += w*v.x; acc.y += w*v.y;
  }
  XS[lm*12 + z] = acc;
}

// ---- Layer-1 combine ------------------------------------------------------
__global__ void k3_combine1(const float2* __restrict__ XS,
                            const float2* __restrict__ W1,
                            const int4* __restrict__ LMN,
                            float2* __restrict__ ZS) {
  int r = blockIdx.x;
  int4 t = LMN[r];
  int l = t.x, m = t.y, n = t.z;
  int sm = l*l + l + m, sn = l*l + l + n;
  int zb = threadIdx.x >> 5, o = threadIdx.x & 31;
  float2 acc = make_float2(0.f, 0.f);
  #pragma unroll
  for (int i = 0; i < 3; ++i) {
    float2 xv = XS[sm*12 + zb*3 + i];
    float2 wv = W1[(sn*3 + i)*32 + o];
    acc.x += xv.x*wv.x + xv.y*wv.y;   // xv * conj(wv)
    acc.y += xv.y*wv.x - xv.x*wv.y;
  }
  ZS[(size_t)r*128 + threadIdx.x] = acc;
}

// ---- Inverse Wigner: Gp[(mi,ni)][b*ZC+zl] ---------------------------------
template<int NB, int NL>
__global__ void k4_wiginv(const float2* __restrict__ ZS,
                          const float* __restrict__ WT,
                          float2* __restrict__ Gp,
                          int Ztot, int z0, int ZC) {
  constexpr int NF = 2*NL - 1;
  constexpr int NJ = (NB + 7)/8;
  int bx = blockIdx.x;
  int mi = bx / NF, ni = bx % NF;
  int m = mi - (NL-1), n = ni - (NL-1);
  int zl = blockIdx.y*32 + (threadIdx.x & 31);
  int g  = threadIdx.x >> 5;     // 0..7
  float2 acc[NJ];
  #pragma unroll
  for (int j = 0; j < NJ; ++j) acc[j] = make_float2(0.f, 0.f);
  int am = m < 0 ? -m : m, an = n < 0 ? -n : n;
  int lmin = am > an ? am : an;
  for (int l = lmin; l < NL; ++l) {
    int L = 2*l + 1;
    int spec = l*(4*l*l - 1)/3 + (m + l)*L + (n + l);
    float2 zv = ZS[(size_t)spec*Ztot + z0 + zl];
    #pragma unroll
    for (int j = 0; j < NJ; ++j) {
      int b = g + j*8;
      if (b < NB) {
        float w = WT[(size_t)spec*NB + b];
        acc[j].x += w*zv.x; acc[j].y += w*zv.y;
      }
    }
  }
  size_t base = (size_t)bx * ((size_t)ZC*NB) + zl;
  #pragma unroll
  for (int j = 0; j < NJ; ++j) {
    int b = g + j*8;
    if (b < NB) Gp[base + (size_t)b*ZC] = acc[j];
  }
}

// ---- idft stage A ----------------------------------------------------------
template<int NF, int NA>
__global__ __launch_bounds__(256)
void k5a_idft(const float2* __restrict__ G, const float2* __restrict__ EI,
              float2* __restrict__ T2, int rowsC) {
  int ni = blockIdx.x;
  int at = blockIdx.y;
  int row = blockIdx.z*256 + threadIdx.x;
  if (row >= rowsC) return;
  float2 acc[8];
  #pragma unroll
  for (int u = 0; u < 8; ++u) acc[u] = make_float2(0.f, 0.f);
  const float2* gp = G + (size_t)ni*rowsC + row;
  for (int mi = 0; mi < NF; ++mi) {
    float2 gv = gp[(size_t)mi*NF*rowsC];
    #pragma unroll
    for (int u = 0; u < 8; ++u) {
      int a = at*8 + u; if (a >= NA) a = NA-1;       // clamp (result discarded)
      float2 e = EI[a*NF + mi];                      // block-uniform -> s_load
      acc[u].x += e.x*gv.x - e.y*gv.y;
      acc[u].y += e.x*gv.y + e.y*gv.x;
    }
  }
  #pragma unroll
  for (int u = 0; u < 8; ++u) {
    int a = at*8 + u;
    if (a < NA) T2[((size_t)a*NF + ni)*rowsC + row] = acc[u];
  }
}

// ---- idft stage B: contract ni, Re + bias + relu, write Ht[(a,g)][b*Zt+z] --
template<int NF, int NA>
__global__ __launch_bounds__(256)
void k5b_idft(const float2* __restrict__ T2, const float2* __restrict__ EI,
              const float* __restrict__ bias, float* __restrict__ Ht,
              int ZC, int z0, int Zt, int NB, int Cout, int rowsC) {
  constexpr int NAIT = NA/4;
  __shared__ float2 EIs[NA*NF];
  __shared__ float2 Ts[NF][64];
  int a = blockIdx.x;
  int row0 = blockIdx.y*64;
  int t = threadIdx.x;
  for (int i = t; i < NA*NF; i += 256) EIs[i] = EI[i];
  for (int i = t; i < NF*64; i += 256) {
    int ni = i >> 6, rr = i & 63;
    int row = row0 + rr;
    Ts[ni][rr] = (row < rowsC) ? T2[((size_t)a*NF + ni)*rowsC + row]
                               : make_float2(0.f, 0.f);
  }
  __syncthreads();
  int r = t & 63, gq = t >> 6;
  int row = row0 + r;
  if (row >= rowsC) return;
  int b = row / ZC, zl = row - b*ZC;
  int z = z0 + zl;
  float bv = bias[z % Cout];
  float facc[NAIT];
  #pragma unroll
  for (int it = 0; it < NAIT; ++it) facc[it] = 0.f;
  for (int ni = 0; ni < NF; ++ni) {
    float2 tv = Ts[ni][r];
    #pragma unroll
    for (int it = 0; it < NAIT; ++it) {
      float2 e = EIs[(gq + 4*it)*NF + ni];     // wave-uniform -> broadcast
      facc[it] += e.x*tv.x - e.y*tv.y;
    }
  }
  size_t hb = (size_t)(a*NA)*(size_t)(NB*Zt) + (size_t)b*Zt + z;
  #pragma unroll
  for (int it = 0; it < NAIT; ++it) {
    int g = gq + 4*it;
    Ht[hb + (size_t)g*(NB*Zt)] = fmaxf(facc[it] + bv, 0.f);
  }
}

// ---- fwd DFT stage 1: contract g (7-wide load batching for ILP) -----------
template<int NA, int NF>
__global__ __launch_bounds__(256)
void kf1_dftg(const float* __restrict__ Ht, const float2* __restrict__ EF,
              float2* __restrict__ XA, int NB, int Zt, int z0, int ZC, int rowsC) {
  int a = blockIdx.x;
  int kt = blockIdx.y;                 // 0..1 (14 freqs each)
  int row = blockIdx.z*256 + threadIdx.x;
  if (row >= rowsC) return;
  int b = row / ZC, zl = row - b*ZC;
  size_t hbase = (size_t)(a*NA)*(size_t)(NB*Zt) + (size_t)b*Zt + z0 + zl;
  float2 acc[14];
  #pragma unroll
  for (int u = 0; u < 14; ++u) acc[u] = make_float2(0.f, 0.f);
  for (int g0 = 0; g0 < NA; g0 += 7) {
    float hv[7];
    #pragma unroll
    for (int j = 0; j < 7; ++j)
      hv[j] = Ht[hbase + (size_t)(g0 + j)*(NB*Zt)];
    #pragma unroll
    for (int j = 0; j < 7; ++j) {
      #pragma unroll
      for (int u = 0; u < 14; ++u) {
        int ki = kt*14 + u; if (ki >= NF) ki = NF-1;
        float2 e = EF[ki*NA + g0 + j];           // block-uniform -> s_load
        acc[u].x += hv[j]*e.x; acc[u].y += hv[j]*e.y;
      }
    }
  }
  #pragma unroll
  for (int u = 0; u < 14; ++u) {
    int ki = kt*14 + u;
    if (ki < NF) XA[((size_t)a*NF + ki)*rowsC + row] = acc[u];
  }
}

// ---- fwd DFT stage 2 --------------------------------------------------------
template<int NA, int NF>
__global__ __launch_bounds__(256)
void kf2_dfta(const float2* __restrict__ XA, const float2* __restrict__ EF,
              float2* __restrict__ Xf, int rowsC) {
  int ki = blockIdx.x;                 // 0..NF-1
  int mt = blockIdx.y;                 // 0..1
  int row = blockIdx.z*256 + threadIdx.x;
  if (row >= rowsC) return;
  float2 acc[14];
  #pragma unroll
  for (int u = 0; u < 14; ++u) acc[u] = make_float2(0.f, 0.f);
  const float2* xp = XA + (size_t)ki*rowsC + row;
  for (int a = 0; a < NA; ++a) {
    float2 v = xp[(size_t)a*NF*rowsC];
    #pragma unroll
    for (int u = 0; u < 14; ++u) {
      int mi = mt*14 + u; if (mi >= NF) mi = NF-1;
      float2 e = EF[mi*NA + a];
      acc[u].x += v.x*e.x - v.y*e.y;
      acc[u].y += v.x*e.y + v.y*e.x;
    }
  }
  #pragma unroll
  for (int u = 0; u < 14; ++u) {
    int mi = mt*14 + u;
    if (mi < NF) Xf[((size_t)mi*NF + ki)*rowsC + row] = acc[u];
  }
}

// ---- forward Wigner --------------------------------------------------------
__global__ void k8_wigfwd(const float2* __restrict__ XfT,
                          const float* __restrict__ WT,
                          const int4* __restrict__ LMN,
                          float2* __restrict__ XS,
                          int NB, int ZC, int z0, int Ztot) {
  int spec = blockIdx.x;
  int zl = threadIdx.x;
  int4 t = LMN[spec];
  int mi = t.y + 13, ni = t.z + 13;
  float2 acc = make_float2(0.f, 0.f);
  size_t base = (size_t)(mi*27 + ni) * ((size_t)NB*ZC);
  for (int b = 0; b < NB; ++b) {
    float w = WT[(size_t)spec*NB + b];
    float2 v = XfT[base + (size_t)b*ZC + zl];
    acc.x += w*v.x; acc.y += w*v.y;
  }
  XS[(size_t)spec*Ztot + z0 + zl] = acc;
}

// ---- SO3 combine on MFMA v2: full-M blocks, swizzled conflict-free LDS ----
// C = conj(X)[M x K] * W[K x N] complex -> real A2[M][2K] x B2[2K][2N].
// Block: ALL M rows (<=7 row-tiles of 16) x 64 n2-cols; W read exactly once.
// LDS frag layout: slot = tile*64 + lane, 8 shorts -> lane-consecutive b128.
// task = (l, c0) with c0 in n2 units, step 64.
template<int CI, int CO>
__global__ __launch_bounds__(256)
void k9_mfma2(const float2* __restrict__ XS, const float2* __restrict__ W,
              const int2* __restrict__ tasks, float* __restrict__ ZSo) {
  constexpr int Zin = 4*CI, Zout = 4*CO;
  constexpr int LOG2CI = (CI==32) ? 5 : (CI==64) ? 6 : 7;
  int2 tk = tasks[blockIdx.x];
  int l = tk.x, c0 = tk.y;
  int L = 2*l + 1;
  int ofs = l*(4*l*l - 1)/3;
  int M = 4*L, K = L*CI, N2 = 2*L*CO;
  int MT = (M + 15) >> 4;               // row-tiles, <= 7
  __shared__ __align__(16) unsigned short Ah[3584], Al[3584];  // 7*64 slots
  __shared__ __align__(16) unsigned short Bh[2048], Bl[2048];  // 4*64 slots
  int t = threadIdx.x;
  int wv = t >> 6, ln = t & 63;
  fv4 acc[7];
  #pragma unroll
  for (int mt = 0; mt < 7; ++mt) acc[mt] = fv4{0.f, 0.f, 0.f, 0.f};
  int nc0 = c0 >> 1;
  int NC = L*CO;

  for (int kc0 = 0; kc0 < K; kc0 += 16) {
    // ---- stage A: MT*16 rows x 16 complex-k, swizzled ----
    #pragma unroll
    for (int h = 0; h < 7; ++h) {
      if (h < MT) {
        int row = h*16 + (t & 15);
        int kci = t >> 4;
        int kc = kc0 + kci;
        float xr = 0.f, xi = 0.f;
        if (row < M) {
          int am = row >> 2, azb = row & 3;
          int kq = kc >> LOG2CI, ii = kc & (CI-1);
          float2 xv = XS[((size_t)(ofs + am*L + kq))*Zin + (size_t)azb*CI + ii];
          xr = xv.x; xi = -xv.y;
        }
        unsigned short rh = bhi(xr); unsigned short rl = bhi(xr - bf2f(rh));
        unsigned short ih = bhi(xi); unsigned short il = bhi(xi - bf2f(ih));
        int slot = h*64 + (row & 15) + 16*(kci >> 2);
        int pos = slot*8 + (kci & 3)*2;
        *(unsigned*)&Ah[pos] = (unsigned)rh | ((unsigned)ih << 16);
        *(unsigned*)&Al[pos] = (unsigned)rl | ((unsigned)il << 16);
      }
    }
    // ---- stage B: 16 complex-k x 32 complex-n, swizzled ----
    #pragma unroll
    for (int h2 = 0; h2 < 2; ++h2) {
      int idx = t + 256*h2;
      int nci = idx & 31, kci = idx >> 5;        // kci 0..15
      int nc = nc0 + nci;
      int kc = kc0 + kci;
      float wr = 0.f, wi = 0.f;
      if (nc < NC) {
        int n = nc / CO, o = nc - n*CO;
        int kq = kc >> LOG2CI, ii = kc & (CI-1);
        float2 wvv = W[((size_t)(ofs + n*L + kq)*CI + ii)*CO + o];
        wr = wvv.x; wi = wvv.y;
      }
      unsigned short rh = bhi(wr); unsigned short rl = bhi(wr - bf2f(rh));
      unsigned short ih = bhi(wi); unsigned short il = bhi(wi - bf2f(ih));
      int r0 = 2*nci, r1 = 2*nci + 1;
      int s0 = ((r0 >> 4)*64 + (r0 & 15) + 16*(kci >> 2))*8 + (kci & 3)*2;
      int s1 = ((r1 >> 4)*64 + (r1 & 15) + 16*(kci >> 2))*8 + (kci & 3)*2;
      // row 2nci: (Wr, -Wi) ; row 2nci+1: (Wi, Wr)
      *(unsigned*)&Bh[s0] = (unsigned)rh | ((unsigned)(ih ^ 0x8000) << 16);
      *(unsigned*)&Bl[s0] = (unsigned)rl | ((unsigned)(il ^ 0x8000) << 16);
      *(unsigned*)&Bh[s1] = (unsigned)ih | ((unsigned)rh << 16);
      *(unsigned*)&Bl[s1] = (unsigned)il | ((unsigned)rl << 16);
    }
    __syncthreads();
    sv8 fbh = *(const sv8*)&Bh[(wv*64 + ln)*8];
    sv8 fbl = *(const sv8*)&Bl[(wv*64 + ln)*8];
    #pragma unroll
    for (int mt = 0; mt < 7; ++mt) {
      if (mt < MT) {
        sv8 fah = *(const sv8*)&Ah[(mt*64 + ln)*8];
        sv8 fal = *(const sv8*)&Al[(mt*64 + ln)*8];
        acc[mt] = __builtin_amdgcn_mfma_f32_16x16x32_bf16(fah, fbh, acc[mt], 0, 0, 0);
        acc[mt] = __builtin_amdgcn_mfma_f32_16x16x32_bf16(fah, fbl, acc[mt], 0, 0, 0);
        acc[mt] = __builtin_amdgcn_mfma_f32_16x16x32_bf16(fal, fbh, acc[mt], 0, 0, 0);
      }
    }
    __syncthreads();
  }
  // epilogue: C/D layout: col = lane&15, row = (lane>>4)*4 + reg
  int col = ln & 15;
  int n2 = c0 + wv*16 + col;
  if (n2 < N2) {
    int nc = n2 >> 1, comp = n2 & 1;
    int n = nc / CO, o = nc - n*CO;
    #pragma unroll
    for (int mt = 0; mt < 7; ++mt) {
      if (mt < MT) {
        #pragma unroll
        for (int g = 0; g < 4; ++g) {
          int R = mt*16 + (ln >> 4)*4 + g;
          if (R < M) {
            int m = R >> 2, zb = R & 3;
            ZSo[(((size_t)(ofs + m*L + n))*Zout + (size_t)zb*CO + o)*2 + comp] = acc[mt][g];
          }
        }
      }
    }
  }
}

// ---- integrate (Ht layout) + FC -------------------------------------------
__global__ void k10a_colsum(const float* __restrict__ Ht, float* __restrict__ Cp,
                            int rows, int cols, int rowsPer) {
  int col = blockIdx.x*256 + threadIdx.x;
  if (col >= cols) return;
  int r0 = blockIdx.y*rowsPer;
  int r1 = r0 + rowsPer; if (r1 > rows) r1 = rows;
  float acc = 0.f;
  for (int r = r0; r < r1; ++r) acc += Ht[(size_t)r*cols + col];
  Cp[(size_t)blockIdx.y*cols + col] = acc;
}

__global__ void k10a_fin(const float* __restrict__ Cp, const float* __restrict__ QW,
                         float* __restrict__ S, int Zt, int NB, int nparts) {
  int z = blockIdx.x*64 + threadIdx.x;
  if (z >= Zt) return;
  int cols = NB*Zt;
  float acc = 0.f;
  for (int b = 0; b < NB; ++b) {
    float cs = 0.f;
    for (int p = 0; p < nparts; ++p) cs += Cp[(size_t)p*cols + b*Zt + z];
    acc += cs * QW[b];
  }
  S[z] = acc;
}

__global__ void k10b_fc(const float* __restrict__ S,
                        const float* __restrict__ Wout,
                        const float* __restrict__ bout,
                        float* __restrict__ out) {
  int t = threadIdx.x;
  if (t < 40) {
    int zb = t / 10, c = t % 10;
    float acc = bout[c];
    for (int o = 0; o < 40; ++o) acc += S[zb*40 + o] * Wout[c*40 + o];
    out[zb*10 + c] = acc;
  }
}

// ===========================================================================
// Host side
// ===========================================================================

// upload blob offsets (bytes)
static const size_t U_VT    = 0;                     // 29260 f
static const size_t U_LAM   = 117040;                // 784 f
static const size_t U_QW224 = U_LAM + 3136;          // 224 f
static const size_t U_QW56  = U_QW224 + 896;         // 56 f
static const size_t U_QW28  = U_QW56 + 224;          // 28 f
static const size_t U_TK2   = U_QW28 + 112;          // 1024 int2 each
static const size_t U_TK3   = U_TK2 + 8192;
static const size_t U_TK4   = U_TK3 + 8192;
static const size_t U_TK5   = U_TK4 + 8192;
static const size_t U_BYTES = U_TK5 + 8192;

struct WsOff {
  size_t up, ws2t, wi28t, wf28t, wi14t, wf14t, e224, ef56, ei56, ef28, ei28,
         lmn28, lmn14, idx1, zs1, xsf, zso, HA, HB, S, fixedEnd;
};

static WsOff wsOff() {
  WsOff o; size_t c = 0;
  auto take = [&](size_t bytes) { size_t r = c; c = (c + bytes + 255) & ~(size_t)255; return r; };
  o.up    = take(U_BYTES);
  o.ws2t  = take((size_t)784*224*4);
  o.wi28t = take((size_t)29260*56*4);
  o.wf28t = take((size_t)3654*56*4);
  o.wi14t = take((size_t)3654*28*4);
  o.wf14t = take((size_t)3654*28*4);
  o.e224  = take((size_t)55*224*8);
  o.ef56  = take((size_t)27*56*8);
  o.ei56  = take((size_t)56*55*8);
  o.ef28  = take((size_t)27*28*8);
  o.ei28  = take((size_t)28*27*8);
  o.lmn28 = take((size_t)29260*16);
  o.lmn14 = take((size_t)3654*16);
  o.idx1  = take(784*4);
  o.zs1   = take((size_t)29260*128*8);
  o.xsf   = take((size_t)3654*512*8);
  o.zso   = take((size_t)3654*512*8);
  o.HA    = take((size_t)128*56*56*56*4);
  o.HB    = take((size_t)512*28*28*28*4);
  o.S     = take(16*4480*4 + 1024);
  o.fixedEnd = c;
  return o;
}

// Jacobi eigensolver for symmetric n x n (n <= 55), A destroyed.
static void jacobi_sym(int n, double* A, double* V, double* lam) {
  for (int i = 0; i < n*n; ++i) V[i] = 0.0;
  for (int i = 0; i < n; ++i) V[i*n + i] = 1.0;
  for (int sweep = 0; sweep < 100; ++sweep) {
    double off = 0.0;
    for (int p = 0; p < n; ++p)
      for (int q = p+1; q < n; ++q) off += A[p*n+q]*A[p*n+q];
    if (off < 1e-22) break;
    for (int p = 0; p < n-1; ++p) {
      for (int q = p+1; q < n; ++q) {
        double apq = A[p*n+q];
        if (fabs(apq) < 1e-300) continue;
        double theta = (A[q*n+q] - A[p*n+p]) / (2.0*apq);
        double tt = (theta >= 0 ? 1.0 : -1.0) / (fabs(theta) + sqrt(theta*theta + 1.0));
        double cc = 1.0/sqrt(tt*tt + 1.0), ss = tt*cc;
        for (int i = 0; i < n; ++i) {
          double aip = A[i*n+p], aiq = A[i*n+q];
          A[i*n+p] = cc*aip - ss*aiq;
          A[i*n+q] = ss*aip + cc*aiq;
        }
        for (int i = 0; i < n; ++i) {
          double api = A[p*n+i], aqi = A[q*n+i];
          A[p*n+i] = cc*api - ss*aqi;
          A[q*n+i] = ss*api + cc*aqi;
        }
        for (int i = 0; i < n; ++i) {
          double vip = V[i*n+p], viq = V[i*n+q];
          V[i*n+p] = cc*vip - ss*viq;
          V[i*n+q] = ss*vip + cc*viq;
        }
      }
    }
  }
  for (int i = 0; i < n; ++i) lam[i] = A[i*n+i];
}

extern "C" void kernel_launch(void* const* d_in, const int* in_sizes, int n_in,
                              void* d_out, int out_size, void* d_ws, size_t ws_size,
                              hipStream_t stream) {
  (void)in_sizes; (void)n_in; (void)out_size;
  const WsOff off = wsOff();
  const size_t MINAB = (size_t)3080*32*56*8;      // 44.2 MB: layer-1 T2 chunk
  if (ws_size < off.fixedEnd + 2*MINAB) return;

  const float*  x    = (const float*)d_in[0];
  const float2* w1   = (const float2*)d_in[1];
  const float*  b1   = (const float*)d_in[2];
  const float2* w2   = (const float2*)d_in[3];
  const float*  b2   = (const float*)d_in[4];
  const float2* w3   = (const float2*)d_in[5];
  const float*  b3   = (const float*)d_in[6];
  const float2* w4   = (const float2*)d_in[7];
  const float*  b4   = (const float*)d_in[8];
  const float2* w5   = (const float2*)d_in[9];
  const float*  b5   = (const float*)d_in[10];
  const float*  wout = (const float*)d_in[11];
  const float*  bout = (const float*)d_in[12];
  float* outp = (float*)d_out;
  char* ws = (char*)d_ws;

  // ------------- host: eigen-seeds + quad weights + task tables -----------
  char* hb = new char[U_BYTES];                 // leaked; graph keeps the ptr
  memset(hb, 0, U_BYTES);
  float* hVT  = (float*)(hb + U_VT);
  float* hLAM = (float*)(hb + U_LAM);
  float* hQW224 = (float*)(hb + U_QW224);
  float* hQW56  = (float*)(hb + U_QW56);
  float* hQW28  = (float*)(hb + U_QW28);
  int2*  hTK[4] = {(int2*)(hb + U_TK2), (int2*)(hb + U_TK3),
                   (int2*)(hb + U_TK4), (int2*)(hb + U_TK5)};

  auto quadw = [](int b, double* w) {
    for (int j = 0; j < 2*b; ++j) {
      double s = 0.0;
      for (int k = 0; k < b; ++k)
        s += sin(M_PI*(2*j+1)*(2*k+1)/(4.0*b)) / (double)(2*k+1);
      w[j] = 2.0/b * sin(M_PI*(2*j+1)/(4.0*b)) * s * 2.0*M_PI/((2.0*b)*(2.0*b));
    }
  };
  std::vector<double> qw224(224), qw56(56), qw28v(28);
  quadw(112, qw224.data()); quadw(28, qw56.data()); quadw(14, qw28v.data());
  for (int j = 0; j < 224; ++j) hQW224[j] = (float)qw224[j];
  for (int j = 0; j < 56;  ++j) hQW56[j]  = (float)qw56[j];
  for (int j = 0; j < 28;  ++j) hQW28[j]  = (float)qw28v[j];

  const int NMAX = 55;
  std::vector<double> T(NMAX*NMAX), V(NMAX*NMAX), lam(NMAX);
  for (int l = 0; l < 28; ++l) {
    int n = 2*l + 1;
    std::fill(T.begin(), T.begin() + n*n, 0.0);
    for (int i = 0; i < n-1; ++i) {
      int m = i - l;
      double c = sqrt((double)(l*(l+1)) - (double)(m*(m+1)));
      T[i*n + i + 1] = 0.5*c;
      T[(i+1)*n + i] = 0.5*c;
    }
    jacobi_sym(n, T.data(), V.data(), lam.data());
    size_t vofs = (size_t)l*(4*l*l - 1)/3;
    for (int i = 0; i < n*n; ++i) hVT[vofs + i] = (float)V[i];
    for (int k = 0; k < n; ++k)  hLAM[l*l + k] = (float)lam[k];
  }

  // MFMA task tables: (l, c0), c0 step 64 over N2 = 2*L*CO; l descending
  const int COv[4] = {64, 128, 64, 40};
  int tcnt[4];
  for (int li = 0; li < 4; ++li) {
    int cnt = 0;
    for (int l = 13; l >= 0; --l) {
      int L = 2*l + 1, N2 = 2*L*COv[li];
      for (int c0 = 0; c0 < N2; c0 += 64)
        hTK[li][cnt++] = make_int2(l, c0);
    }
    tcnt[li] = cnt;   // 392, 784, 392, 252
  }

  // ------------------- device pointers -------------------
  const float*  dWS2T  = (const float*)(ws + off.ws2t);
  const float*  dWI28T = (const float*)(ws + off.wi28t);
  const float*  dWF28T = (const float*)(ws + off.wf28t);
  const float*  dWI14T = (const float*)(ws + off.wi14t);
  const float*  dWF14T = (const float*)(ws + off.wf14t);
  const float2* dE224  = (const float2*)(ws + off.e224);
  const float2* dEF56  = (const float2*)(ws + off.ef56);
  const float2* dEI56  = (const float2*)(ws + off.ei56);
  const float2* dEF28  = (const float2*)(ws + off.ef28);
  const float2* dEI28  = (const float2*)(ws + off.ei28);
  const int4*   dLMN28 = (const int4*)(ws + off.lmn28);
  const int4*   dLMN14 = (const int4*)(ws + off.lmn14);
  const int*    dIDX1  = (const int*)(ws + off.idx1);
  const float*  dUVT   = (const float*)(ws + off.up + U_VT);
  const float*  dULAM  = (const float*)(ws + off.up + U_LAM);
  const float*  dUQW224= (const float*)(ws + off.up + U_QW224);
  const float*  dUQW56 = (const float*)(ws + off.up + U_QW56);
  const float*  dUQW28 = (const float*)(ws + off.up + U_QW28);
  const int2*   dTK2   = (const int2*)(ws + off.up + U_TK2);
  const int2*   dTK3   = (const int2*)(ws + off.up + U_TK3);
  const int2*   dTK4   = (const int2*)(ws + off.up + U_TK4);
  const int2*   dTK5   = (const int2*)(ws + off.up + U_TK5);
  float2* dZS1 = (float2*)(ws + off.zs1);
  float2* dXSF = (float2*)(ws + off.xsf);
  float2* dZSO = (float2*)(ws + off.zso);
  float*  dHA  = (float*)(ws + off.HA);
  float*  dHB  = (float*)(ws + off.HB);
  float*  dCp  = (float*)(ws + off.S);                  // 16 x 4480 partials
  float*  dS   = (float*)(ws + off.S + 16*4480*4);      // 160 sums

  size_t ab = ((ws_size - off.fixedEnd)/2) & ~(size_t)255;
  char* Abuf = ws + off.fixedEnd;
  char* Bbuf = Abuf + ab;
  float2* dA = (float2*)Abuf;
  float2* dB = (float2*)Bbuf;
  // xf1/xs1 alias the A buffer (dead before first k4 use of A)
  float2* dXF1 = (float2*)Abuf;                          // 12*224*55 f2
  float2* dXS1 = (float2*)(Abuf + 1182720);              // 784*12 f2

  // ------------------- upload seeds + generate tables -------------------
  hipMemcpyAsync(ws + off.up, hb, U_BYTES, hipMemcpyHostToDevice, stream);
  kg_idx<<<28, 256, 0, stream>>>((int4*)(ws + off.lmn28), (int4*)(ws + off.lmn14),
                                 (int*)(ws + off.idx1));
  kg_tw<<<72, 256, 0, stream>>>((float2*)(ws + off.e224), (float2*)(ws + off.ef56),
                                (float2*)(ws + off.ei56), (float2*)(ws + off.ef28),
                                (float2*)(ws + off.ei28));
  kg_wig<<<784, 224, 0, stream>>>(dUVT, dULAM, dUQW224, nullptr,
                                  (float*)(ws + off.ws2t), 224, 0);
  kg_wig<<<29260, 64, 0, stream>>>(dUVT, dULAM, nullptr, dLMN28,
                                   (float*)(ws + off.wi28t), 56, 1);
  kg_wig<<<3654, 64, 0, stream>>>(dUVT, dULAM, dUQW56, dLMN14,
                                  (float*)(ws + off.wf28t), 56, 2);
  kg_wig<<<3654, 64, 0, stream>>>(dUVT, dULAM, nullptr, dLMN14,
                                  (float*)(ws + off.wi14t), 28, 1);
  kg_wig<<<3654, 64, 0, stream>>>(dUVT, dULAM, dUQW28, dLMN14,
                                  (float*)(ws + off.wf14t), 28, 2);

  // chunk pickers (bytes-per-z of the largest chunk buffer)
  auto pickPow2 = [&](int Zt, size_t perz)->int {
    int zc = Zt;
    while (zc > 32 && perz*(size_t)zc > ab) zc >>= 1;
    return zc;
  };
  int zc1  = pickPow2(128, (size_t)3080*56*8);   // layer-1 inverse (T2 biggest)
  int zcF2 = pickPow2(128, (size_t)56*27*56*8);  // layer-2 fwd (XA biggest)
  int zcI  = pickPow2(256, (size_t)756*28*8);    // b=14 inverse
  int zcF  = pickPow2(256, (size_t)28*27*28*8);  // b=14 fwd (Zt<=512 chunks)

  // ------------------- layer 1: s2_conv(112 -> 28) -------------------
  k1_dft_alpha<<<12*224, 64, 0, stream>>>(x, dE224, dXF1);
  k2_s2wig<<<784, 64, 0, stream>>>(dXF1, dWS2T, dIDX1, dXS1);
  k3_combine1<<<29260, 128, 0, stream>>>(dXS1, w1, dLMN28, dZS1);
  for (int z0 = 0; z0 < 128; z0 += zc1) {
    int rowsC = zc1*56;
    k4_wiginv<56,28><<<dim3(3025, zc1/32), 256, 0, stream>>>(dZS1, dWI28T, dA, 128, z0, zc1);
    k5a_idft<55,56><<<dim3(55, 7, (rowsC+255)/256), 256, 0, stream>>>(dA, dEI56, dB, rowsC);
    k5b_idft<55,56><<<dim3(56, (rowsC+63)/64), 256, 0, stream>>>(dB, dEI56, b1, dHA,
                                                                 zc1, z0, 128, 56, 32, rowsC);
  }

  // ------------------- layer 2: so3_conv(28 -> 14), 32->64 -----------
  for (int z0 = 0; z0 < 128; z0 += zcF2) {
    int rowsC = zcF2*56;
    kf1_dftg<56,27><<<dim3(56, 2, (rowsC+255)/256), 256, 0, stream>>>(dHA, dEF56, dA,
                                                                      56, 128, z0, zcF2, rowsC);
    kf2_dfta<56,27><<<dim3(27, 2, (rowsC+255)/256), 256, 0, stream>>>(dA, dEF56, dB, rowsC);
    k8_wigfwd<<<3654, zcF2, 0, stream>>>(dB, dWF28T, dLMN14, dXSF, 56, zcF2, z0, 128);
  }
  k9_mfma2<32,64><<<tcnt[0], 256, 0, stream>>>(dXSF, w2, dTK2, (float*)dZSO);
  for (int z0 = 0; z0 < 256; z0 += zcI) {
    int rowsC = zcI*28;
    k4_wiginv<28,14><<<dim3(729, zcI/32), 256, 0, stream>>>(dZSO, dWI14T, dA, 256, z0, zcI);
    k5a_idft<27,28><<<dim3(27, 4, (rowsC+255)/256), 256, 0, stream>>>(dA, dEI28, dB, rowsC);
    k5b_idft<27,28><<<dim3(28, (rowsC+63)/64), 256, 0, stream>>>(dB, dEI28, b2, dHB,
                                                                 zcI, z0, 256, 28, 64, rowsC);
  }

  // ------------------- layer 3: so3_conv(14), 64->128 ----------------
  for (int z0 = 0; z0 < 256; z0 += zcF) {
    int rowsC = zcF*28;
    kf1_dftg<28,27><<<dim3(28, 2, (rowsC+255)/256), 256, 0, stream>>>(dHB, dEF28, dA,
                                                                      28, 256, z0, zcF, rowsC);
    kf2_dfta<28,27><<<dim3(27, 2, (rowsC+255)/256), 256, 0, stream>>>(dA, dEF28, dB, rowsC);
    k8_wigfwd<<<3654, zcF, 0, stream>>>(dB, dWF14T, dLMN14, dXSF, 28, zcF, z0, 256);
  }
  k9_mfma2<64,128><<<tcnt[1], 256, 0, stream>>>(dXSF, w3, dTK3, (float*)dZSO);
  for (int z0 = 0; z0 < 512; z0 += zcI) {
    int rowsC = zcI*28;
    k4_wiginv<28,14><<<dim3(729, zcI/32), 256, 0, stream>>>(dZSO, dWI14T, dA, 512, z0, zcI);
    k5a_idft<27,28><<<dim3(27, 4, (rowsC+255)/256), 256, 0, stream>>>(dA, dEI28, dB, rowsC);
    k5b_idft<27,28><<<dim3(28, (rowsC+63)/64), 256, 0, stream>>>(dB, dEI28, b3, dHA,
                                                                 zcI, z0, 512, 28, 128, rowsC);
  }

  // ------------------- layer 4: so3_conv(14), 128->64 ----------------
  for (int z0 = 0; z0 < 512; z0 += zcF) {
    int rowsC = zcF*28;
    kf1_dftg<28,27><<<dim3(28, 2, (rowsC+255)/256), 256, 0, stream>>>(dHA, dEF28, dA,
                                                                      28, 512, z0, zcF, rowsC);
    kf2_dfta<28,27><<<dim3(27, 2, (rowsC+255)/256), 256, 0, stream>>>(dA, dEF28, dB, rowsC);
    k8_wigfwd<<<3654, zcF, 0, stream>>>(dB, dWF14T, dLMN14, dXSF, 28, zcF, z0, 512);
  }
  k9_mfma2<128,64><<<tcnt[2], 256, 0, stream>>>(dXSF, w4, dTK4, (float*)dZSO);
  for (int z0 = 0; z0 < 256; z0 += zcI) {
    int rowsC = zcI*28;
    k4_wiginv<28,14><<<dim3(729, zcI/32), 256, 0, stream>>>(dZSO, dWI14T, dA, 256, z0, zcI);
    k5a_idft<27,28><<<dim3(27, 4, (rowsC+255)/256), 256, 0, stream>>>(dA, dEI28, dB, rowsC);
    k5b_idft<27,28><<<dim3(28, (rowsC+63)/64), 256, 0, stream>>>(dB, dEI28, b4, dHB,
                                                                 zcI, z0, 256, 28, 64, rowsC);
  }

  // ------------------- layer 5: so3_conv(14), 64->40 -----------------
  for (int z0 = 0; z0 < 256; z0 += zcF) {
    int rowsC = zcF*28;
    kf1_dftg<28,27><<<dim3(28, 2, (rowsC+255)/256), 256, 0, stream>>>(dHB, dEF28, dA,
                                                                      28, 256, z0, zcF, rowsC);
    kf2_dfta<28,27><<<dim3(27, 2, (rowsC+255)/256), 256, 0, stream>>>(dA, dEF28, dB, rowsC);
    k8_wigfwd<<<3654, zcF, 0, stream>>>(dB, dWF14T, dLMN14, dXSF, 28, zcF, z0, 256);
  }
  k9_mfma2<64,40><<<tcnt[3], 256, 0, stream>>>(dXSF, w5, dTK5, (float*)dZSO);
  {
    // Z = 160 in one chunk (T2 = 27 MB <= ab)
    int rowsC = 160*28;
    k4_wiginv<28,14><<<dim3(729, 5), 256, 0, stream>>>(dZSO, dWI14T, dA, 160, 0, 160);
    k5a_idft<27,28><<<dim3(27, 4, (rowsC+255)/256), 256, 0, stream>>>(dA, dEI28, dB, rowsC);
    k5b_idft<27,28><<<dim3(28, (rowsC+63)/64), 256, 0, stream>>>(dB, dEI28, b5, dHA,
                                                                 160, 0, 160, 28, 40, rowsC);
  }

  // ------------------- integrate + FC -------------------
  k10a_colsum<<<dim3(18, 16), 256, 0, stream>>>(dHA, dCp, 784, 4480, 49);
  k10a_fin<<<3, 64, 0, stream>>>(dCp, dUQW28, dS, 160, 28, 16);
  k10b_fc<<<1, 64, 0, stream>>>(dS, wout, bout, outp);
}